// Round 9
// baseline (2220.882 us; speedup 1.0000x reference)
//
#include <hip/hip_runtime.h>
#include <hip/hip_bf16.h>
#include <stdint.h>

// CausalSelfAttention: B=8, T=2048, C=128, H=4, D=32. fp32 in / fp32 out.
//   qkv_mfma: qkv = x @ w_qkv + b (Q pre-scaled log2e/sqrt(D); V -> [bh][d][t])
//   attn:     barrier-free transposed-S flash attention. One wave = one
//             (bh, 32-query chunk). K/V fragments loaded DIRECTLY from global
//             (K: coalesced 1KB per chunk; V: L1-resident lines), register
//             double-buffer prefetch. P stays in registers (R8-validated
//             S^T=K*Q^T -> exp -> pk2 -> mfma_f32_16x16x16bf16_1k PV).
//   out_mfma: out = y @ w_proj + b (fp32 out)
// ws: qb 4MB | kb 4MB | vtb 4MB | yb bf16 4MB = 16MB

#define T_SEQ 2048
#define C_EMBD 128
#define NH 4
#define HD 32
#define BATCH 8
#define BHT (BATCH * NH)

typedef float f4  __attribute__((ext_vector_type(4)));
typedef short bh8 __attribute__((ext_vector_type(8)));
typedef short bh4 __attribute__((ext_vector_type(4)));
typedef unsigned long long ull;

__device__ __forceinline__ unsigned short f2bf(float f) {
    union { float f; unsigned u; } v; v.f = f;
    return (unsigned short)((v.u + 0x7fffu + ((v.u >> 16) & 1u)) >> 16);
}
__device__ __forceinline__ unsigned pk2(float a, float b) {
    float2 t; t.x = a; t.y = b;
    __hip_bfloat162 h = __float22bfloat162_rn(t);   // v_cvt_pk_bf16_f32
    union { __hip_bfloat162 h; unsigned u; } c; c.h = h;
    return c.u;
}
__device__ __forceinline__ ull pk4(float a, float b, float c, float d) {
    return (ull)pk2(a, b) | ((ull)pk2(c, d) << 32);
}

// ---------------------------------------------------------------------------
// Kernel 1: qkv = x @ w_qkv + b_qkv via MFMA. Grid (nt=3, mt=256).
// ---------------------------------------------------------------------------
__global__ __launch_bounds__(256) void qkv_mfma(const float* __restrict__ x,
                                                const float* __restrict__ w,
                                                const float* __restrict__ bias,
                                                unsigned short* __restrict__ qb,
                                                unsigned short* __restrict__ kb,
                                                unsigned short* __restrict__ vtb) {
    constexpr int XR = 136;
    constexpr int WR = 136;
    constexpr int VR = 72;
    __shared__ __align__(16) unsigned short xs[64 * XR];
    __shared__ __align__(16) unsigned short wt[128 * WR];
    __shared__ __align__(16) unsigned short vt[128 * VR];

    const int nt = blockIdx.x;        // 0=Q 1=K 2=V
    const int mt = blockIdx.y;        // row tile of 64
    const int t0g = mt * 64;
    const int b = t0g >> 11;
    const int t0 = t0g & 2047;
    const int tid = threadIdx.x;
    const int wave = tid >> 6;
    const int lane = tid & 63;
    const int col = lane & 15;
    const int quad = lane >> 4;

    for (int i = 0; i < 8; ++i) {
        const int idx = tid + i * 256;
        const int row = idx >> 5, c4 = idx & 31;
        const float4 xv = *(const float4*)(x + (size_t)(t0g + row) * C_EMBD + c4 * 4);
        *(ull*)(&xs[row * XR + c4 * 4]) = pk4(xv.x, xv.y, xv.z, xv.w);
    }
    for (int i = 0; i < 16; ++i) {
        const int idx = tid + i * 256;
        const int n = idx & 127, k4 = idx >> 7;
        const float w0 = w[(k4 * 4 + 0) * 384 + nt * 128 + n];
        const float w1 = w[(k4 * 4 + 1) * 384 + nt * 128 + n];
        const float w2 = w[(k4 * 4 + 2) * 384 + nt * 128 + n];
        const float w3 = w[(k4 * 4 + 3) * 384 + nt * 128 + n];
        *(ull*)(&wt[n * WR + k4 * 4]) = pk4(w0, w1, w2, w3);
    }
    __syncthreads();

    f4 acc[8];
#pragma unroll
    for (int nf = 0; nf < 8; ++nf) {
        const float bv = bias[nt * 128 + nf * 16 + col];
        acc[nf] = (f4){bv, bv, bv, bv};
    }
#pragma unroll
    for (int ch = 0; ch < 4; ++ch) {
        const bh8 af = *(const bh8*)(&xs[(wave * 16 + col) * XR + ch * 32 + quad * 8]);
#pragma unroll
        for (int nf = 0; nf < 8; ++nf) {
            const bh8 bf = *(const bh8*)(&wt[(nf * 16 + col) * WR + ch * 32 + quad * 8]);
            acc[nf] = __builtin_amdgcn_mfma_f32_16x16x32_bf16(af, bf, acc[nf], 0, 0, 0);
        }
    }

    const int mrow = wave * 16 + quad * 4;
    if (nt < 2) {
        unsigned short* outp = (nt == 0) ? qb : kb;
        const float sc = (nt == 0) ? 0.25503485952317864f : 1.0f;  // log2(e)/sqrt(32)
#pragma unroll
        for (int nf = 0; nf < 8; ++nf) {
            const int n = nf * 16 + col, h = n >> 5, d = n & 31;
            const size_t base = ((size_t)(b * NH + h) * T_SEQ + t0 + mrow) * HD + d;
#pragma unroll
            for (int r = 0; r < 4; ++r)
                outp[base + (size_t)r * HD] = f2bf(acc[nf][r] * sc);
        }
    } else {
#pragma unroll
        for (int nf = 0; nf < 8; ++nf) {
            const int n = nf * 16 + col;
            *(ull*)(&vt[n * VR + mrow]) = pk4(acc[nf][0], acc[nf][1], acc[nf][2], acc[nf][3]);
        }
        __syncthreads();
        for (int i = 0; i < 16; ++i) {
            const int idx = tid + i * 256;
            const int c = idx >> 5, dw = idx & 31;
            const int h2 = c >> 5, d2 = c & 31;
            const unsigned v0 = *(const unsigned*)(&vt[c * VR + dw * 2]);
            *(unsigned*)(vtb + ((size_t)(b * NH + h2) * HD + d2) * T_SEQ + t0 + dw * 2) = v0;
        }
    }
}

// ---------------------------------------------------------------------------
// Kernel 2: barrier-free attention. Grid 512 x 256 thr; wave w of block i
// owns (bh = (i&7)*4+w, q-chunk c = 63-(i>>3), queries c*32..c*32+31).
// Longest-job-first dispatch; no LDS, no syncthreads.
// Per 64-key tile kt: K-frags (4x b128, coalesced 1KB/chunk) and V^T-frags
// (8x b64, line-reusing) prefetched one tile ahead in registers.
// S^T = mfma_16x16x32(kf, qf) -> lane P^T[key=quad*4+r][q=col]; exp2; pack;
// PV: yaccT[dim][q] += mfma_16x16x16bf16_1k(vf, pf).
// ---------------------------------------------------------------------------
__global__ __launch_bounds__(256) void attn(const unsigned short* __restrict__ qb,
                                            const unsigned short* __restrict__ kb,
                                            const unsigned short* __restrict__ vtb,
                                            unsigned short* __restrict__ y) {
    const int tid = threadIdx.x;
    const int wave = tid >> 6;
    const int lane = tid & 63;
    const int col = lane & 15;
    const int quad = lane >> 4;
    const int blk = blockIdx.x;
    const int c = 63 - (blk >> 3);            // q-chunk, heavy first
    const int bh = ((blk & 7) << 2) + wave;
    const int q0 = c * 32;
    const int ntiles = (c >> 1) + 1;

    const unsigned short* kbase = kb + (size_t)bh * T_SEQ * HD;
    const unsigned short* vbase = vtb + (size_t)bh * HD * T_SEQ;

    bh8 qfrag[2];
#pragma unroll
    for (int mi = 0; mi < 2; ++mi)
        qfrag[mi] = *(const bh8*)(qb + ((size_t)bh * T_SEQ + q0 + mi * 16 + col) * HD + quad * 8);

    f4 yacc[2][2];
#pragma unroll
    for (int mi = 0; mi < 2; ++mi)
#pragma unroll
        for (int dh = 0; dh < 2; ++dh) yacc[mi][dh] = (f4){0.f, 0.f, 0.f, 0.f};
    float lsum[2] = {0.f, 0.f};

    bh8 kf[2][4];
    bh4 vf[2][4][2];
#pragma unroll
    for (int f = 0; f < 4; ++f) {
        kf[0][f] = *(const bh8*)(kbase + (size_t)(f * 16 + col) * HD + quad * 8);
        vf[0][f][0] = *(const bh4*)(vbase + (size_t)col * T_SEQ + f * 16 + quad * 4);
        vf[0][f][1] = *(const bh4*)(vbase + (size_t)(16 + col) * T_SEQ + f * 16 + quad * 4);
    }

    // main (unmasked) tiles
    for (int kt = 0; kt + 1 < ntiles; ++kt) {
        const int cur = kt & 1, nxt = cur ^ 1;
        const int kn = (kt + 1) * 64;
#pragma unroll
        for (int f = 0; f < 4; ++f) {
            kf[nxt][f] = *(const bh8*)(kbase + (size_t)(kn + f * 16 + col) * HD + quad * 8);
            vf[nxt][f][0] = *(const bh4*)(vbase + (size_t)col * T_SEQ + kn + f * 16 + quad * 4);
            vf[nxt][f][1] = *(const bh4*)(vbase + (size_t)(16 + col) * T_SEQ + kn + f * 16 + quad * 4);
        }
#pragma unroll
        for (int mi = 0; mi < 2; ++mi)
#pragma unroll
            for (int f = 0; f < 4; ++f) {
                f4 z = {0.f, 0.f, 0.f, 0.f};
                z = __builtin_amdgcn_mfma_f32_16x16x32_bf16(kf[cur][f], qfrag[mi], z, 0, 0, 0);
                float p[4];
#pragma unroll
                for (int r = 0; r < 4; ++r) p[r] = __builtin_amdgcn_exp2f(z[r]);
                lsum[mi] += p[0] + p[1] + p[2] + p[3];
                union { unsigned u[2]; bh4 v; } pf;
                pf.u[0] = pk2(p[0], p[1]);
                pf.u[1] = pk2(p[2], p[3]);
                yacc[mi][0] = __builtin_amdgcn_mfma_f32_16x16x16bf16_1k(vf[cur][f][0], pf.v, yacc[mi][0], 0, 0, 0);
                yacc[mi][1] = __builtin_amdgcn_mfma_f32_16x16x16bf16_1k(vf[cur][f][1], pf.v, yacc[mi][1], 0, 0, 0);
            }
    }

    // last (diagonal) tile, masked
    {
        const int kt = ntiles - 1;
        const int cur = kt & 1;
        const int kb0 = kt * 64;
#pragma unroll
        for (int mi = 0; mi < 2; ++mi)
#pragma unroll
            for (int f = 0; f < 4; ++f) {
                const int dlt = kb0 + f * 16 - q0 - mi * 16;  // wave-uniform
                if (dlt > 0) continue;                        // fully masked chunk
                const bool edge = (dlt == 0);
                f4 z = {0.f, 0.f, 0.f, 0.f};
                z = __builtin_amdgcn_mfma_f32_16x16x32_bf16(kf[cur][f], qfrag[mi], z, 0, 0, 0);
                float p[4];
#pragma unroll
                for (int r = 0; r < 4; ++r) {
                    const float e = __builtin_amdgcn_exp2f(z[r]);
                    p[r] = (edge && (quad * 4 + r > col)) ? 0.f : e;
                }
                lsum[mi] += p[0] + p[1] + p[2] + p[3];
                union { unsigned u[2]; bh4 v; } pf;
                pf.u[0] = pk2(p[0], p[1]);
                pf.u[1] = pk2(p[2], p[3]);
                yacc[mi][0] = __builtin_amdgcn_mfma_f32_16x16x16bf16_1k(vf[cur][f][0], pf.v, yacc[mi][0], 0, 0, 0);
                yacc[mi][1] = __builtin_amdgcn_mfma_f32_16x16x16bf16_1k(vf[cur][f][1], pf.v, yacc[mi][1], 0, 0, 0);
            }
    }

    // epilogue: l over quads (lanes col, col+16, col+32, col+48), packed store
    const int bb = bh >> 2, hh = bh & 3;
#pragma unroll
    for (int mi = 0; mi < 2; ++mi) {
        float t = lsum[mi];
        t += __shfl_xor(t, 16);
        t += __shfl_xor(t, 32);
        const float inv = 1.0f / t;
        const size_t row = (size_t)bb * T_SEQ + q0 + mi * 16 + col;
#pragma unroll
        for (int dh = 0; dh < 2; ++dh) {
            *(ull*)(y + row * C_EMBD + hh * HD + dh * 16 + quad * 4) =
                pk4(yacc[mi][dh][0] * inv, yacc[mi][dh][1] * inv,
                    yacc[mi][dh][2] * inv, yacc[mi][dh][3] * inv);
        }
    }
}

// ---------------------------------------------------------------------------
// Kernel 3: out = y @ w_proj + b_proj via MFMA. Grid 256.
// ---------------------------------------------------------------------------
__global__ __launch_bounds__(256) void out_mfma(const unsigned short* __restrict__ y,
                                                const float* __restrict__ w,
                                                const float* __restrict__ bias,
                                                float* __restrict__ out) {
    constexpr int YR = 136;
    constexpr int WR = 136;
    __shared__ __align__(16) unsigned short ys[64 * YR];
    __shared__ __align__(16) unsigned short wt[128 * WR];

    const int mt = blockIdx.x;
    const int row0 = mt * 64;
    const int tid = threadIdx.x;
    const int wave = tid >> 6;
    const int lane = tid & 63;
    const int col = lane & 15;
    const int quad = lane >> 4;

    for (int i = 0; i < 4; ++i) {
        const int idx = tid + i * 256;
        const int row = idx >> 4, q8 = idx & 15;
        const uint4 v = *(const uint4*)(y + (size_t)(row0 + row) * C_EMBD + q8 * 8);
        *(uint4*)(&ys[row * YR + q8 * 8]) = v;
    }
    for (int i = 0; i < 16; ++i) {
        const int idx = tid + i * 256;
        const int n = idx & 127, k4 = idx >> 7;
        const float w0 = w[(k4 * 4 + 0) * C_EMBD + n];
        const float w1 = w[(k4 * 4 + 1) * C_EMBD + n];
        const float w2 = w[(k4 * 4 + 2) * C_EMBD + n];
        const float w3 = w[(k4 * 4 + 3) * C_EMBD + n];
        *(ull*)(&wt[n * WR + k4 * 4]) = pk4(w0, w1, w2, w3);
    }
    __syncthreads();

    f4 acc[8];
#pragma unroll
    for (int nf = 0; nf < 8; ++nf) {
        const float bv = bias[nf * 16 + col];
        acc[nf] = (f4){bv, bv, bv, bv};
    }
#pragma unroll
    for (int ch = 0; ch < 4; ++ch) {
        const bh8 af = *(const bh8*)(&ys[(wave * 16 + col) * YR + ch * 32 + quad * 8]);
#pragma unroll
        for (int nf = 0; nf < 8; ++nf) {
            const bh8 bf = *(const bh8*)(&wt[(nf * 16 + col) * WR + ch * 32 + quad * 8]);
            acc[nf] = __builtin_amdgcn_mfma_f32_16x16x32_bf16(af, bf, acc[nf], 0, 0, 0);
        }
    }

    const int mrow = wave * 16 + quad * 4;
#pragma unroll
    for (int nf = 0; nf < 8; ++nf)
#pragma unroll
        for (int r = 0; r < 4; ++r)
            out[(size_t)(row0 + mrow + r) * C_EMBD + nf * 16 + col] = acc[nf][r];
}

extern "C" void kernel_launch(void* const* d_in, const int* in_sizes, int n_in,
                              void* d_out, int out_size, void* d_ws, size_t ws_size,
                              hipStream_t stream) {
    const float* x      = (const float*)d_in[0];
    const float* w_qkv  = (const float*)d_in[1];
    const float* b_qkv  = (const float*)d_in[2];
    const float* w_proj = (const float*)d_in[3];
    const float* b_proj = (const float*)d_in[4];
    float* out = (float*)d_out;

    unsigned short* qb  = (unsigned short*)d_ws;                   // 4 MB
    unsigned short* kb  = qb + (size_t)BHT * T_SEQ * HD;           // 4 MB
    unsigned short* vtb = kb + (size_t)BHT * T_SEQ * HD;           // 4 MB
    unsigned short* yb  = vtb + (size_t)BHT * T_SEQ * HD;          // 4 MB (bf16 y)

    qkv_mfma<<<dim3(3, 256), 256, 0, stream>>>(x, w_qkv, b_qkv, qb, kb, vtb);
    attn<<<512, 256, 0, stream>>>(qb, kb, vtb, yb);
    out_mfma<<<256, 256, 0, stream>>>(yb, w_proj, b_proj, out);
}

// Round 10
// 140.557 us; speedup vs baseline: 15.8006x; 15.8006x over previous
//
#include <hip/hip_runtime.h>
#include <hip/hip_bf16.h>
#include <stdint.h>

// CausalSelfAttention: B=8, T=2048, C=128, H=4, D=32. fp32 in / fp32 out.
//   qkv_mfma: qkv = x @ w_qkv + b (Q pre-scaled log2e/sqrt(D); V -> [bh][d][t])
//   attn:     barrier-free transposed-S flash attention. One wave = one
//             (bh, 32-query chunk); K/V frags direct from global; register
//             double-buffer as TWO NAMED SETS (A/B), unroll-by-2 pipeline so
//             every buffer index is compile-time (R9 bug: runtime kf[cur]
//             demoted the arrays to scratch -> 2.2ms latency death).
//   out_mfma: out = y @ w_proj + b (fp32 out)
// ws: qb 4MB | kb 4MB | vtb 4MB | yb bf16 4MB = 16MB

#define T_SEQ 2048
#define C_EMBD 128
#define NH 4
#define HD 32
#define BATCH 8
#define BHT (BATCH * NH)

typedef float f4  __attribute__((ext_vector_type(4)));
typedef short bh8 __attribute__((ext_vector_type(8)));
typedef short bh4 __attribute__((ext_vector_type(4)));
typedef unsigned long long ull;

__device__ __forceinline__ unsigned short f2bf(float f) {
    union { float f; unsigned u; } v; v.f = f;
    return (unsigned short)((v.u + 0x7fffu + ((v.u >> 16) & 1u)) >> 16);
}
__device__ __forceinline__ unsigned pk2(float a, float b) {
    float2 t; t.x = a; t.y = b;
    __hip_bfloat162 h = __float22bfloat162_rn(t);   // v_cvt_pk_bf16_f32
    union { __hip_bfloat162 h; unsigned u; } c; c.h = h;
    return c.u;
}
__device__ __forceinline__ ull pk4(float a, float b, float c, float d) {
    return (ull)pk2(a, b) | ((ull)pk2(c, d) << 32);
}

// ---------------------------------------------------------------------------
// Kernel 1: qkv = x @ w_qkv + b_qkv via MFMA. Grid (nt=3, mt=256).
// ---------------------------------------------------------------------------
__global__ __launch_bounds__(256) void qkv_mfma(const float* __restrict__ x,
                                                const float* __restrict__ w,
                                                const float* __restrict__ bias,
                                                unsigned short* __restrict__ qb,
                                                unsigned short* __restrict__ kb,
                                                unsigned short* __restrict__ vtb) {
    constexpr int XR = 136;
    constexpr int WR = 136;
    constexpr int VR = 72;
    __shared__ __align__(16) unsigned short xs[64 * XR];
    __shared__ __align__(16) unsigned short wt[128 * WR];
    __shared__ __align__(16) unsigned short vt[128 * VR];

    const int nt = blockIdx.x;        // 0=Q 1=K 2=V
    const int mt = blockIdx.y;        // row tile of 64
    const int t0g = mt * 64;
    const int b = t0g >> 11;
    const int t0 = t0g & 2047;
    const int tid = threadIdx.x;
    const int wave = tid >> 6;
    const int lane = tid & 63;
    const int col = lane & 15;
    const int quad = lane >> 4;

    for (int i = 0; i < 8; ++i) {
        const int idx = tid + i * 256;
        const int row = idx >> 5, c4 = idx & 31;
        const float4 xv = *(const float4*)(x + (size_t)(t0g + row) * C_EMBD + c4 * 4);
        *(ull*)(&xs[row * XR + c4 * 4]) = pk4(xv.x, xv.y, xv.z, xv.w);
    }
    for (int i = 0; i < 16; ++i) {
        const int idx = tid + i * 256;
        const int n = idx & 127, k4 = idx >> 7;
        const float w0 = w[(k4 * 4 + 0) * 384 + nt * 128 + n];
        const float w1 = w[(k4 * 4 + 1) * 384 + nt * 128 + n];
        const float w2 = w[(k4 * 4 + 2) * 384 + nt * 128 + n];
        const float w3 = w[(k4 * 4 + 3) * 384 + nt * 128 + n];
        *(ull*)(&wt[n * WR + k4 * 4]) = pk4(w0, w1, w2, w3);
    }
    __syncthreads();

    f4 acc[8];
#pragma unroll
    for (int nf = 0; nf < 8; ++nf) {
        const float bv = bias[nt * 128 + nf * 16 + col];
        acc[nf] = (f4){bv, bv, bv, bv};
    }
#pragma unroll
    for (int ch = 0; ch < 4; ++ch) {
        const bh8 af = *(const bh8*)(&xs[(wave * 16 + col) * XR + ch * 32 + quad * 8]);
#pragma unroll
        for (int nf = 0; nf < 8; ++nf) {
            const bh8 bf = *(const bh8*)(&wt[(nf * 16 + col) * WR + ch * 32 + quad * 8]);
            acc[nf] = __builtin_amdgcn_mfma_f32_16x16x32_bf16(af, bf, acc[nf], 0, 0, 0);
        }
    }

    const int mrow = wave * 16 + quad * 4;
    if (nt < 2) {
        unsigned short* outp = (nt == 0) ? qb : kb;
        const float sc = (nt == 0) ? 0.25503485952317864f : 1.0f;  // log2(e)/sqrt(32)
#pragma unroll
        for (int nf = 0; nf < 8; ++nf) {
            const int n = nf * 16 + col, h = n >> 5, d = n & 31;
            const size_t base = ((size_t)(b * NH + h) * T_SEQ + t0 + mrow) * HD + d;
#pragma unroll
            for (int r = 0; r < 4; ++r)
                outp[base + (size_t)r * HD] = f2bf(acc[nf][r] * sc);
        }
    } else {
#pragma unroll
        for (int nf = 0; nf < 8; ++nf) {
            const int n = nf * 16 + col;
            *(ull*)(&vt[n * VR + mrow]) = pk4(acc[nf][0], acc[nf][1], acc[nf][2], acc[nf][3]);
        }
        __syncthreads();
        for (int i = 0; i < 16; ++i) {
            const int idx = tid + i * 256;
            const int c = idx >> 5, dw = idx & 31;
            const int h2 = c >> 5, d2 = c & 31;
            const unsigned v0 = *(const unsigned*)(&vt[c * VR + dw * 2]);
            *(unsigned*)(vtb + ((size_t)(b * NH + h2) * HD + d2) * T_SEQ + t0 + dw * 2) = v0;
        }
    }
}

// ---------------------------------------------------------------------------
// Kernel 2: barrier-free attention, named-register double buffer.
// Wave w of block i owns (bh=(i&7)*4+w, chunk c=63-(i>>3), 32 queries).
// S^T = mfma_16x16x32(kf, qf) -> P^T in regs -> mfma_16x16x16bf16_1k PV.
// ---------------------------------------------------------------------------
__global__ __launch_bounds__(256) void attn(const unsigned short* __restrict__ qb,
                                            const unsigned short* __restrict__ kb,
                                            const unsigned short* __restrict__ vtb,
                                            unsigned short* __restrict__ y) {
    const int tid = threadIdx.x;
    const int wave = tid >> 6;
    const int lane = tid & 63;
    const int col = lane & 15;
    const int quad = lane >> 4;
    const int blk = blockIdx.x;
    const int c = 63 - (blk >> 3);            // q-chunk, heavy first
    const int bh = ((blk & 7) << 2) + wave;
    const int q0 = c * 32;
    const int ntiles = (c >> 1) + 1;

    const unsigned short* kbase = kb + (size_t)bh * T_SEQ * HD;
    const unsigned short* vbase = vtb + (size_t)bh * HD * T_SEQ;

    bh8 qfrag[2];
#pragma unroll
    for (int mi = 0; mi < 2; ++mi)
        qfrag[mi] = *(const bh8*)(qb + ((size_t)bh * T_SEQ + q0 + mi * 16 + col) * HD + quad * 8);

    f4 yacc[2][2];
#pragma unroll
    for (int mi = 0; mi < 2; ++mi)
#pragma unroll
        for (int dh = 0; dh < 2; ++dh) yacc[mi][dh] = (f4){0.f, 0.f, 0.f, 0.f};
    float lsum[2] = {0.f, 0.f};

    // two NAMED buffer sets -> compile-time indices only (never runtime-select)
    bh8 kfA[4], kfB[4];
    bh4 vfA[4][2], vfB[4][2];

    auto prefetch = [&](bh8 (&KF)[4], bh4 (&VF)[4][2], int kt) {
        const int kn = kt * 64;
#pragma unroll
        for (int f = 0; f < 4; ++f) {
            KF[f] = *(const bh8*)(kbase + (size_t)(kn + f * 16 + col) * HD + quad * 8);
            VF[f][0] = *(const bh4*)(vbase + (size_t)col * T_SEQ + kn + f * 16 + quad * 4);
            VF[f][1] = *(const bh4*)(vbase + (size_t)(16 + col) * T_SEQ + kn + f * 16 + quad * 4);
        }
    };
    auto compute = [&](const bh8 (&KF)[4], const bh4 (&VF)[4][2]) {
#pragma unroll
        for (int mi = 0; mi < 2; ++mi)
#pragma unroll
            for (int f = 0; f < 4; ++f) {
                f4 z = {0.f, 0.f, 0.f, 0.f};
                z = __builtin_amdgcn_mfma_f32_16x16x32_bf16(KF[f], qfrag[mi], z, 0, 0, 0);
                float p[4];
#pragma unroll
                for (int r = 0; r < 4; ++r) p[r] = __builtin_amdgcn_exp2f(z[r]);
                lsum[mi] += p[0] + p[1] + p[2] + p[3];
                union { unsigned u[2]; bh4 v; } pf;
                pf.u[0] = pk2(p[0], p[1]);
                pf.u[1] = pk2(p[2], p[3]);
                yacc[mi][0] = __builtin_amdgcn_mfma_f32_16x16x16bf16_1k(VF[f][0], pf.v, yacc[mi][0], 0, 0, 0);
                yacc[mi][1] = __builtin_amdgcn_mfma_f32_16x16x16bf16_1k(VF[f][1], pf.v, yacc[mi][1], 0, 0, 0);
            }
    };
    auto compute_masked = [&](const bh8 (&KF)[4], const bh4 (&VF)[4][2], int kb0) {
#pragma unroll
        for (int mi = 0; mi < 2; ++mi)
#pragma unroll
            for (int f = 0; f < 4; ++f) {
                const int dlt = kb0 + f * 16 - q0 - mi * 16;  // wave-uniform
                if (dlt > 0) continue;                        // fully masked chunk
                const bool edge = (dlt == 0);
                f4 z = {0.f, 0.f, 0.f, 0.f};
                z = __builtin_amdgcn_mfma_f32_16x16x32_bf16(KF[f], qfrag[mi], z, 0, 0, 0);
                float p[4];
#pragma unroll
                for (int r = 0; r < 4; ++r) {
                    const float e = __builtin_amdgcn_exp2f(z[r]);
                    p[r] = (edge && (quad * 4 + r > col)) ? 0.f : e;
                }
                lsum[mi] += p[0] + p[1] + p[2] + p[3];
                union { unsigned u[2]; bh4 v; } pf;
                pf.u[0] = pk2(p[0], p[1]);
                pf.u[1] = pk2(p[2], p[3]);
                yacc[mi][0] = __builtin_amdgcn_mfma_f32_16x16x16bf16_1k(VF[f][0], pf.v, yacc[mi][0], 0, 0, 0);
                yacc[mi][1] = __builtin_amdgcn_mfma_f32_16x16x16bf16_1k(VF[f][1], pf.v, yacc[mi][1], 0, 0, 0);
            }
    };

    prefetch(kfA, vfA, 0);
    for (int kt = 0; kt < ntiles; kt += 2) {
        const bool hasB = (kt + 1 < ntiles);
        if (hasB) prefetch(kfB, vfB, kt + 1);
        if (kt == ntiles - 1) compute_masked(kfA, vfA, kt * 64);
        else                  compute(kfA, vfA);
        if (hasB) {
            if (kt + 2 < ntiles) prefetch(kfA, vfA, kt + 2);
            if (kt + 1 == ntiles - 1) compute_masked(kfB, vfB, (kt + 1) * 64);
            else                      compute(kfB, vfB);
        }
    }

    // epilogue: l over quads (lanes col, col+16, col+32, col+48), packed store
    const int bb = bh >> 2, hh = bh & 3;
#pragma unroll
    for (int mi = 0; mi < 2; ++mi) {
        float t = lsum[mi];
        t += __shfl_xor(t, 16);
        t += __shfl_xor(t, 32);
        const float inv = 1.0f / t;
        const size_t row = (size_t)bb * T_SEQ + q0 + mi * 16 + col;
#pragma unroll
        for (int dh = 0; dh < 2; ++dh) {
            *(ull*)(y + row * C_EMBD + hh * HD + dh * 16 + quad * 4) =
                pk4(yacc[mi][dh][0] * inv, yacc[mi][dh][1] * inv,
                    yacc[mi][dh][2] * inv, yacc[mi][dh][3] * inv);
        }
    }
}

// ---------------------------------------------------------------------------
// Kernel 3: out = y @ w_proj + b_proj via MFMA. Grid 256.
// ---------------------------------------------------------------------------
__global__ __launch_bounds__(256) void out_mfma(const unsigned short* __restrict__ y,
                                                const float* __restrict__ w,
                                                const float* __restrict__ bias,
                                                float* __restrict__ out) {
    constexpr int YR = 136;
    constexpr int WR = 136;
    __shared__ __align__(16) unsigned short ys[64 * YR];
    __shared__ __align__(16) unsigned short wt[128 * WR];

    const int mt = blockIdx.x;
    const int row0 = mt * 64;
    const int tid = threadIdx.x;
    const int wave = tid >> 6;
    const int lane = tid & 63;
    const int col = lane & 15;
    const int quad = lane >> 4;

    for (int i = 0; i < 4; ++i) {
        const int idx = tid + i * 256;
        const int row = idx >> 4, q8 = idx & 15;
        const uint4 v = *(const uint4*)(y + (size_t)(row0 + row) * C_EMBD + q8 * 8);
        *(uint4*)(&ys[row * YR + q8 * 8]) = v;
    }
    for (int i = 0; i < 16; ++i) {
        const int idx = tid + i * 256;
        const int n = idx & 127, k4 = idx >> 7;
        const float w0 = w[(k4 * 4 + 0) * C_EMBD + n];
        const float w1 = w[(k4 * 4 + 1) * C_EMBD + n];
        const float w2 = w[(k4 * 4 + 2) * C_EMBD + n];
        const float w3 = w[(k4 * 4 + 3) * C_EMBD + n];
        *(ull*)(&wt[n * WR + k4 * 4]) = pk4(w0, w1, w2, w3);
    }
    __syncthreads();

    f4 acc[8];
#pragma unroll
    for (int nf = 0; nf < 8; ++nf) {
        const float bv = bias[nf * 16 + col];
        acc[nf] = (f4){bv, bv, bv, bv};
    }
#pragma unroll
    for (int ch = 0; ch < 4; ++ch) {
        const bh8 af = *(const bh8*)(&ys[(wave * 16 + col) * YR + ch * 32 + quad * 8]);
#pragma unroll
        for (int nf = 0; nf < 8; ++nf) {
            const bh8 bf = *(const bh8*)(&wt[(nf * 16 + col) * WR + ch * 32 + quad * 8]);
            acc[nf] = __builtin_amdgcn_mfma_f32_16x16x32_bf16(af, bf, acc[nf], 0, 0, 0);
        }
    }

    const int mrow = wave * 16 + quad * 4;
#pragma unroll
    for (int nf = 0; nf < 8; ++nf)
#pragma unroll
        for (int r = 0; r < 4; ++r)
            out[(size_t)(row0 + mrow + r) * C_EMBD + nf * 16 + col] = acc[nf][r];
}

extern "C" void kernel_launch(void* const* d_in, const int* in_sizes, int n_in,
                              void* d_out, int out_size, void* d_ws, size_t ws_size,
                              hipStream_t stream) {
    const float* x      = (const float*)d_in[0];
    const float* w_qkv  = (const float*)d_in[1];
    const float* b_qkv  = (const float*)d_in[2];
    const float* w_proj = (const float*)d_in[3];
    const float* b_proj = (const float*)d_in[4];
    float* out = (float*)d_out;

    unsigned short* qb  = (unsigned short*)d_ws;                   // 4 MB
    unsigned short* kb  = qb + (size_t)BHT * T_SEQ * HD;           // 4 MB
    unsigned short* vtb = kb + (size_t)BHT * T_SEQ * HD;           // 4 MB
    unsigned short* yb  = vtb + (size_t)BHT * T_SEQ * HD;          // 4 MB (bf16 y)

    qkv_mfma<<<dim3(3, 256), 256, 0, stream>>>(x, w_qkv, b_qkv, qb, kb, vtb);
    attn<<<512, 256, 0, stream>>>(qb, kb, vtb, yb);
    out_mfma<<<256, 256, 0, stream>>>(yb, w_proj, b_proj, out);
}

// Round 11
// 132.844 us; speedup vs baseline: 16.7179x; 1.0581x over previous
//
#include <hip/hip_runtime.h>
#include <hip/hip_bf16.h>
#include <stdint.h>

// CausalSelfAttention: B=8, T=2048, C=128, H=4, D=32. fp32 in / fp32 out.
//   qkv_mfma: qkv = x @ w_qkv + b (Q pre-scaled log2e/sqrt(D); V -> [bh][d][t])
//   attn:     barrier-free transposed-S flash attention, SPLIT-K (2 halves):
//             no-max softmax partials are linear -> each half writes fp32
//             unnormalized y-partial + l-partial. 4096 waves (4/SIMD).
//   out_mfma: combines partials ((yp0+yp1)/(l0+l1) per row/head) during LDS
//             staging, then out = y @ w_proj + b.
// ws: qb 4 | kb 4 | vtb 4 | yp0 8 | yp1 8 | l0 .25 | l1 .25 MB

#define T_SEQ 2048
#define C_EMBD 128
#define NH 4
#define HD 32
#define BATCH 8
#define BHT (BATCH * NH)

typedef float f4  __attribute__((ext_vector_type(4)));
typedef short bh8 __attribute__((ext_vector_type(8)));
typedef short bh4 __attribute__((ext_vector_type(4)));
typedef unsigned long long ull;

__device__ __forceinline__ unsigned short f2bf(float f) {
    union { float f; unsigned u; } v; v.f = f;
    return (unsigned short)((v.u + 0x7fffu + ((v.u >> 16) & 1u)) >> 16);
}
__device__ __forceinline__ unsigned pk2(float a, float b) {
    float2 t; t.x = a; t.y = b;
    __hip_bfloat162 h = __float22bfloat162_rn(t);   // v_cvt_pk_bf16_f32
    union { __hip_bfloat162 h; unsigned u; } c; c.h = h;
    return c.u;
}
__device__ __forceinline__ ull pk4(float a, float b, float c, float d) {
    return (ull)pk2(a, b) | ((ull)pk2(c, d) << 32);
}

// ---------------------------------------------------------------------------
// Kernel 1: qkv = x @ w_qkv + b_qkv via MFMA. Grid (nt=3, mt=256).
// ---------------------------------------------------------------------------
__global__ __launch_bounds__(256) void qkv_mfma(const float* __restrict__ x,
                                                const float* __restrict__ w,
                                                const float* __restrict__ bias,
                                                unsigned short* __restrict__ qb,
                                                unsigned short* __restrict__ kb,
                                                unsigned short* __restrict__ vtb) {
    constexpr int XR = 136;
    constexpr int WR = 136;
    constexpr int VR = 72;
    __shared__ __align__(16) unsigned short xs[64 * XR];
    __shared__ __align__(16) unsigned short wt[128 * WR];
    __shared__ __align__(16) unsigned short vt[128 * VR];

    const int nt = blockIdx.x;        // 0=Q 1=K 2=V
    const int mt = blockIdx.y;        // row tile of 64
    const int t0g = mt * 64;
    const int b = t0g >> 11;
    const int t0 = t0g & 2047;
    const int tid = threadIdx.x;
    const int wave = tid >> 6;
    const int lane = tid & 63;
    const int col = lane & 15;
    const int quad = lane >> 4;

    for (int i = 0; i < 8; ++i) {
        const int idx = tid + i * 256;
        const int row = idx >> 5, c4 = idx & 31;
        const float4 xv = *(const float4*)(x + (size_t)(t0g + row) * C_EMBD + c4 * 4);
        *(ull*)(&xs[row * XR + c4 * 4]) = pk4(xv.x, xv.y, xv.z, xv.w);
    }
    for (int i = 0; i < 16; ++i) {
        const int idx = tid + i * 256;
        const int n = idx & 127, k4 = idx >> 7;
        const float w0 = w[(k4 * 4 + 0) * 384 + nt * 128 + n];
        const float w1 = w[(k4 * 4 + 1) * 384 + nt * 128 + n];
        const float w2 = w[(k4 * 4 + 2) * 384 + nt * 128 + n];
        const float w3 = w[(k4 * 4 + 3) * 384 + nt * 128 + n];
        *(ull*)(&wt[n * WR + k4 * 4]) = pk4(w0, w1, w2, w3);
    }
    __syncthreads();

    f4 acc[8];
#pragma unroll
    for (int nf = 0; nf < 8; ++nf) {
        const float bv = bias[nt * 128 + nf * 16 + col];
        acc[nf] = (f4){bv, bv, bv, bv};
    }
#pragma unroll
    for (int ch = 0; ch < 4; ++ch) {
        const bh8 af = *(const bh8*)(&xs[(wave * 16 + col) * XR + ch * 32 + quad * 8]);
#pragma unroll
        for (int nf = 0; nf < 8; ++nf) {
            const bh8 bf = *(const bh8*)(&wt[(nf * 16 + col) * WR + ch * 32 + quad * 8]);
            acc[nf] = __builtin_amdgcn_mfma_f32_16x16x32_bf16(af, bf, acc[nf], 0, 0, 0);
        }
    }

    const int mrow = wave * 16 + quad * 4;
    if (nt < 2) {
        unsigned short* outp = (nt == 0) ? qb : kb;
        const float sc = (nt == 0) ? 0.25503485952317864f : 1.0f;  // log2(e)/sqrt(32)
#pragma unroll
        for (int nf = 0; nf < 8; ++nf) {
            const int n = nf * 16 + col, h = n >> 5, d = n & 31;
            const size_t base = ((size_t)(b * NH + h) * T_SEQ + t0 + mrow) * HD + d;
#pragma unroll
            for (int r = 0; r < 4; ++r)
                outp[base + (size_t)r * HD] = f2bf(acc[nf][r] * sc);
        }
    } else {
#pragma unroll
        for (int nf = 0; nf < 8; ++nf) {
            const int n = nf * 16 + col;
            *(ull*)(&vt[n * VR + mrow]) = pk4(acc[nf][0], acc[nf][1], acc[nf][2], acc[nf][3]);
        }
        __syncthreads();
        for (int i = 0; i < 16; ++i) {
            const int idx = tid + i * 256;
            const int c = idx >> 5, dw = idx & 31;
            const int h2 = c >> 5, d2 = c & 31;
            const unsigned v0 = *(const unsigned*)(&vt[c * VR + dw * 2]);
            *(unsigned*)(vtb + ((size_t)(b * NH + h2) * HD + d2) * T_SEQ + t0 + dw * 2) = v0;
        }
    }
}

// ---------------------------------------------------------------------------
// Kernel 2: barrier-free split-K attention. Grid 1024 x 256 thr.
// Block blk: hs = blk>>3 (0..127): c = 63-(hs>>1) [heavy first], s = hs&1;
// wave w owns bh = (blk&7)*4+w. Wave computes K-tile range [kt0,kt1) of the
// chunk's nt tiles (half0 = ceil, half1 = rest incl. diagonal) and writes
// UNNORMALIZED fp32 y-partial + l-partial to its half's buffers.
// ---------------------------------------------------------------------------
__global__ __launch_bounds__(256) void attn(const unsigned short* __restrict__ qb,
                                            const unsigned short* __restrict__ kb,
                                            const unsigned short* __restrict__ vtb,
                                            float* __restrict__ yp0,
                                            float* __restrict__ yp1,
                                            float* __restrict__ l0,
                                            float* __restrict__ l1) {
    const int tid = threadIdx.x;
    const int wave = tid >> 6;
    const int lane = tid & 63;
    const int col = lane & 15;
    const int quad = lane >> 4;
    const int blk = blockIdx.x;
    const int hs = blk >> 3;
    const int c = 63 - (hs >> 1);             // q-chunk, heavy first
    const int s = hs & 1;                     // K-half
    const int bh = ((blk & 7) << 2) + wave;
    const int q0 = c * 32;
    const int ntk = (c >> 1) + 1;             // total K-tiles for this chunk
    const int n0 = (ntk + 1) >> 1;
    const int kt0 = s ? n0 : 0;
    const int kt1 = s ? ntk : n0;
    const int nloc = kt1 - kt0;

    const unsigned short* kbase = kb + (size_t)bh * T_SEQ * HD;
    const unsigned short* vbase = vtb + (size_t)bh * HD * T_SEQ;

    bh8 qfrag[2];
#pragma unroll
    for (int mi = 0; mi < 2; ++mi)
        qfrag[mi] = *(const bh8*)(qb + ((size_t)bh * T_SEQ + q0 + mi * 16 + col) * HD + quad * 8);

    f4 yacc[2][2];
#pragma unroll
    for (int mi = 0; mi < 2; ++mi)
#pragma unroll
        for (int dh = 0; dh < 2; ++dh) yacc[mi][dh] = (f4){0.f, 0.f, 0.f, 0.f};
    float lsum[2] = {0.f, 0.f};

    // two NAMED buffer sets -> compile-time indices only (R9 lesson: runtime
    // indexing demotes to scratch)
    bh8 kfA[4], kfB[4];
    bh4 vfA[4][2], vfB[4][2];

    auto prefetch = [&](bh8 (&KF)[4], bh4 (&VF)[4][2], int kt) {
        const int kn = kt * 64;
#pragma unroll
        for (int f = 0; f < 4; ++f) {
            KF[f] = *(const bh8*)(kbase + (size_t)(kn + f * 16 + col) * HD + quad * 8);
            VF[f][0] = *(const bh4*)(vbase + (size_t)col * T_SEQ + kn + f * 16 + quad * 4);
            VF[f][1] = *(const bh4*)(vbase + (size_t)(16 + col) * T_SEQ + kn + f * 16 + quad * 4);
        }
    };
    auto compute = [&](const bh8 (&KF)[4], const bh4 (&VF)[4][2]) {
#pragma unroll
        for (int mi = 0; mi < 2; ++mi)
#pragma unroll
            for (int f = 0; f < 4; ++f) {
                f4 z = {0.f, 0.f, 0.f, 0.f};
                z = __builtin_amdgcn_mfma_f32_16x16x32_bf16(KF[f], qfrag[mi], z, 0, 0, 0);
                float p[4];
#pragma unroll
                for (int r = 0; r < 4; ++r) p[r] = __builtin_amdgcn_exp2f(z[r]);
                lsum[mi] += p[0] + p[1] + p[2] + p[3];
                union { unsigned u[2]; bh4 v; } pf;
                pf.u[0] = pk2(p[0], p[1]);
                pf.u[1] = pk2(p[2], p[3]);
                yacc[mi][0] = __builtin_amdgcn_mfma_f32_16x16x16bf16_1k(VF[f][0], pf.v, yacc[mi][0], 0, 0, 0);
                yacc[mi][1] = __builtin_amdgcn_mfma_f32_16x16x16bf16_1k(VF[f][1], pf.v, yacc[mi][1], 0, 0, 0);
            }
    };
    auto compute_masked = [&](const bh8 (&KF)[4], const bh4 (&VF)[4][2], int kb0) {
#pragma unroll
        for (int mi = 0; mi < 2; ++mi)
#pragma unroll
            for (int f = 0; f < 4; ++f) {
                const int dlt = kb0 + f * 16 - q0 - mi * 16;  // wave-uniform
                if (dlt > 0) continue;                        // fully masked chunk
                const bool edge = (dlt == 0);
                f4 z = {0.f, 0.f, 0.f, 0.f};
                z = __builtin_amdgcn_mfma_f32_16x16x32_bf16(KF[f], qfrag[mi], z, 0, 0, 0);
                float p[4];
#pragma unroll
                for (int r = 0; r < 4; ++r) {
                    const float e = __builtin_amdgcn_exp2f(z[r]);
                    p[r] = (edge && (quad * 4 + r > col)) ? 0.f : e;
                }
                lsum[mi] += p[0] + p[1] + p[2] + p[3];
                union { unsigned u[2]; bh4 v; } pf;
                pf.u[0] = pk2(p[0], p[1]);
                pf.u[1] = pk2(p[2], p[3]);
                yacc[mi][0] = __builtin_amdgcn_mfma_f32_16x16x16bf16_1k(VF[f][0], pf.v, yacc[mi][0], 0, 0, 0);
                yacc[mi][1] = __builtin_amdgcn_mfma_f32_16x16x16bf16_1k(VF[f][1], pf.v, yacc[mi][1], 0, 0, 0);
            }
    };

    if (nloc > 0) {
        prefetch(kfA, vfA, kt0);
        for (int i = 0; i < nloc; i += 2) {
            const bool hasB = (i + 1 < nloc);
            if (hasB) prefetch(kfB, vfB, kt0 + i + 1);
            if (kt0 + i == ntk - 1) compute_masked(kfA, vfA, (kt0 + i) * 64);
            else                    compute(kfA, vfA);
            if (hasB) {
                if (i + 2 < nloc) prefetch(kfA, vfA, kt0 + i + 2);
                if (kt0 + i + 1 == ntk - 1) compute_masked(kfB, vfB, (kt0 + i + 1) * 64);
                else                        compute(kfB, vfB);
            }
        }
    }

    // epilogue: partial l (quad-reduced) + unnormalized fp32 y-partial
    const int bb = bh >> 2, hh = bh & 3;
    float* ypw = s ? yp1 : yp0;
    float* lw  = s ? l1  : l0;
#pragma unroll
    for (int mi = 0; mi < 2; ++mi) {
        float t = lsum[mi];
        t += __shfl_xor(t, 16);
        t += __shfl_xor(t, 32);
        if (quad == 0) lw[(size_t)bh * T_SEQ + q0 + mi * 16 + col] = t;
        const size_t row = (size_t)bb * T_SEQ + q0 + mi * 16 + col;
#pragma unroll
        for (int dh = 0; dh < 2; ++dh)
            *(f4*)(ypw + row * C_EMBD + hh * HD + dh * 16 + quad * 4) = yacc[mi][dh];
    }
}

// ---------------------------------------------------------------------------
// Kernel 3: out = ((yp0+yp1)/l) @ w_proj + b_proj via MFMA. Grid 256.
// Normalization folded into LDS staging (l is per-(row,head) scalar).
// ---------------------------------------------------------------------------
__global__ __launch_bounds__(256) void out_mfma(const float* __restrict__ yp0,
                                                const float* __restrict__ yp1,
                                                const float* __restrict__ l0,
                                                const float* __restrict__ l1,
                                                const float* __restrict__ w,
                                                const float* __restrict__ bias,
                                                float* __restrict__ out) {
    constexpr int YR = 136;
    constexpr int WR = 136;
    __shared__ __align__(16) unsigned short ys[64 * YR];
    __shared__ __align__(16) unsigned short wt[128 * WR];
    __shared__ float linv[64][4];

    const int mt = blockIdx.x;
    const int row0 = mt * 64;
    const int tid = threadIdx.x;
    const int wave = tid >> 6;
    const int lane = tid & 63;
    const int col = lane & 15;
    const int quad = lane >> 4;

    {   // per-(row, head) 1/l
        const int row = tid >> 2, h = tid & 3;
        const int gt = row0 + row, b = gt >> 11, t = gt & 2047;
        const size_t idx = ((size_t)(b * NH + h)) * T_SEQ + t;
        linv[row][h] = 1.0f / (l0[idx] + l1[idx]);
    }
    __syncthreads();

    // stage y = (yp0+yp1)*linv -> bf16 LDS
    for (int i = 0; i < 8; ++i) {
        const int idx = tid + i * 256;           // over 64 rows x 32 float4
        const int row = idx >> 5, c4 = idx & 31;
        const size_t base = (size_t)(row0 + row) * C_EMBD + c4 * 4;
        const float4 a = *(const float4*)(yp0 + base);
        const float4 b = *(const float4*)(yp1 + base);
        const float inv = linv[row][c4 >> 3];
        *(ull*)(&ys[row * YR + c4 * 4]) = pk4((a.x + b.x) * inv, (a.y + b.y) * inv,
                                              (a.z + b.z) * inv, (a.w + b.w) * inv);
    }
    for (int i = 0; i < 16; ++i) {
        const int idx = tid + i * 256;
        const int n = idx & 127, k4 = idx >> 7;
        const float w0 = w[(k4 * 4 + 0) * C_EMBD + n];
        const float w1 = w[(k4 * 4 + 1) * C_EMBD + n];
        const float w2 = w[(k4 * 4 + 2) * C_EMBD + n];
        const float w3 = w[(k4 * 4 + 3) * C_EMBD + n];
        *(ull*)(&wt[n * WR + k4 * 4]) = pk4(w0, w1, w2, w3);
    }
    __syncthreads();

    f4 acc[8];
#pragma unroll
    for (int nf = 0; nf < 8; ++nf) {
        const float bv = bias[nf * 16 + col];
        acc[nf] = (f4){bv, bv, bv, bv};
    }
#pragma unroll
    for (int ch = 0; ch < 4; ++ch) {
        const bh8 af = *(const bh8*)(&ys[(wave * 16 + col) * YR + ch * 32 + quad * 8]);
#pragma unroll
        for (int nf = 0; nf < 8; ++nf) {
            const bh8 bf = *(const bh8*)(&wt[(nf * 16 + col) * WR + ch * 32 + quad * 8]);
            acc[nf] = __builtin_amdgcn_mfma_f32_16x16x32_bf16(af, bf, acc[nf], 0, 0, 0);
        }
    }

    const int mrow = wave * 16 + quad * 4;
#pragma unroll
    for (int nf = 0; nf < 8; ++nf)
#pragma unroll
        for (int r = 0; r < 4; ++r)
            out[(size_t)(row0 + mrow + r) * C_EMBD + nf * 16 + col] = acc[nf][r];
}

extern "C" void kernel_launch(void* const* d_in, const int* in_sizes, int n_in,
                              void* d_out, int out_size, void* d_ws, size_t ws_size,
                              hipStream_t stream) {
    const float* x      = (const float*)d_in[0];
    const float* w_qkv  = (const float*)d_in[1];
    const float* b_qkv  = (const float*)d_in[2];
    const float* w_proj = (const float*)d_in[3];
    const float* b_proj = (const float*)d_in[4];
    float* out = (float*)d_out;

    unsigned short* qb  = (unsigned short*)d_ws;                   // 4 MB
    unsigned short* kb  = qb + (size_t)BHT * T_SEQ * HD;           // 4 MB
    unsigned short* vtb = kb + (size_t)BHT * T_SEQ * HD;           // 4 MB
    char* p = (char*)d_ws + (size_t)3 * BHT * T_SEQ * HD * 2;      // 12 MB
    float* yp0 = (float*)p;                                        // 8 MB
    float* yp1 = (float*)(p + (size_t)8 * 1024 * 1024);            // 8 MB
    float* l0  = (float*)(p + (size_t)16 * 1024 * 1024);           // 256 KB
    float* l1  = (float*)(p + (size_t)16 * 1024 * 1024 + 256 * 1024);

    qkv_mfma<<<dim3(3, 256), 256, 0, stream>>>(x, w_qkv, b_qkv, qb, kb, vtb);
    attn<<<1024, 256, 0, stream>>>(qb, kb, vtb, yp0, yp1, l0, l1);
    out_mfma<<<256, 256, 0, stream>>>(yp0, yp1, l0, l1, w_proj, b_proj, out);
}

// Round 12
// 119.310 us; speedup vs baseline: 18.6144x; 1.1134x over previous
//
#include <hip/hip_runtime.h>
#include <hip/hip_bf16.h>
#include <stdint.h>

// CausalSelfAttention: B=8, T=2048, C=128, H=4, D=32. fp32 in / fp32 out.
//   qkv_mfma: qkv = x @ w_qkv + b (Q pre-scaled log2e/sqrt(D); V -> [bh][d][t])
//   attn:     barrier-free transposed-S flash attention, split-K(2), and
//             64 QUERIES PER WAVE (4 q-fragments): per-tile compute ~800cyc
//             >= HBM latency, so prefetch-1 hides it; halves total tiles and
//             V-gather transactions vs 32-q waves.
//   out_mfma: combines partials ((yp0+yp1)/(l0+l1)) during LDS staging, then
//             out = y @ w_proj + b.
// ws: qb 4 | kb 4 | vtb 4 | yp0 8 | yp1 8 | l0 .25 | l1 .25 MB

#define T_SEQ 2048
#define C_EMBD 128
#define NH 4
#define HD 32
#define BATCH 8
#define BHT (BATCH * NH)

typedef float f4  __attribute__((ext_vector_type(4)));
typedef short bh8 __attribute__((ext_vector_type(8)));
typedef short bh4 __attribute__((ext_vector_type(4)));
typedef unsigned long long ull;

__device__ __forceinline__ unsigned short f2bf(float f) {
    union { float f; unsigned u; } v; v.f = f;
    return (unsigned short)((v.u + 0x7fffu + ((v.u >> 16) & 1u)) >> 16);
}
__device__ __forceinline__ unsigned pk2(float a, float b) {
    float2 t; t.x = a; t.y = b;
    __hip_bfloat162 h = __float22bfloat162_rn(t);   // v_cvt_pk_bf16_f32
    union { __hip_bfloat162 h; unsigned u; } c; c.h = h;
    return c.u;
}
__device__ __forceinline__ ull pk4(float a, float b, float c, float d) {
    return (ull)pk2(a, b) | ((ull)pk2(c, d) << 32);
}

// ---------------------------------------------------------------------------
// Kernel 1: qkv = x @ w_qkv + b_qkv via MFMA. Grid (nt=3, mt=256).
// ---------------------------------------------------------------------------
__global__ __launch_bounds__(256) void qkv_mfma(const float* __restrict__ x,
                                                const float* __restrict__ w,
                                                const float* __restrict__ bias,
                                                unsigned short* __restrict__ qb,
                                                unsigned short* __restrict__ kb,
                                                unsigned short* __restrict__ vtb) {
    constexpr int XR = 136;
    constexpr int WR = 136;
    constexpr int VR = 72;
    __shared__ __align__(16) unsigned short xs[64 * XR];
    __shared__ __align__(16) unsigned short wt[128 * WR];
    __shared__ __align__(16) unsigned short vt[128 * VR];

    const int nt = blockIdx.x;        // 0=Q 1=K 2=V
    const int mt = blockIdx.y;        // row tile of 64
    const int t0g = mt * 64;
    const int b = t0g >> 11;
    const int t0 = t0g & 2047;
    const int tid = threadIdx.x;
    const int wave = tid >> 6;
    const int lane = tid & 63;
    const int col = lane & 15;
    const int quad = lane >> 4;

    for (int i = 0; i < 8; ++i) {
        const int idx = tid + i * 256;
        const int row = idx >> 5, c4 = idx & 31;
        const float4 xv = *(const float4*)(x + (size_t)(t0g + row) * C_EMBD + c4 * 4);
        *(ull*)(&xs[row * XR + c4 * 4]) = pk4(xv.x, xv.y, xv.z, xv.w);
    }
    for (int i = 0; i < 16; ++i) {
        const int idx = tid + i * 256;
        const int n = idx & 127, k4 = idx >> 7;
        const float w0 = w[(k4 * 4 + 0) * 384 + nt * 128 + n];
        const float w1 = w[(k4 * 4 + 1) * 384 + nt * 128 + n];
        const float w2 = w[(k4 * 4 + 2) * 384 + nt * 128 + n];
        const float w3 = w[(k4 * 4 + 3) * 384 + nt * 128 + n];
        *(ull*)(&wt[n * WR + k4 * 4]) = pk4(w0, w1, w2, w3);
    }
    __syncthreads();

    f4 acc[8];
#pragma unroll
    for (int nf = 0; nf < 8; ++nf) {
        const float bv = bias[nt * 128 + nf * 16 + col];
        acc[nf] = (f4){bv, bv, bv, bv};
    }
#pragma unroll
    for (int ch = 0; ch < 4; ++ch) {
        const bh8 af = *(const bh8*)(&xs[(wave * 16 + col) * XR + ch * 32 + quad * 8]);
#pragma unroll
        for (int nf = 0; nf < 8; ++nf) {
            const bh8 bf = *(const bh8*)(&wt[(nf * 16 + col) * WR + ch * 32 + quad * 8]);
            acc[nf] = __builtin_amdgcn_mfma_f32_16x16x32_bf16(af, bf, acc[nf], 0, 0, 0);
        }
    }

    const int mrow = wave * 16 + quad * 4;
    if (nt < 2) {
        unsigned short* outp = (nt == 0) ? qb : kb;
        const float sc = (nt == 0) ? 0.25503485952317864f : 1.0f;  // log2(e)/sqrt(32)
#pragma unroll
        for (int nf = 0; nf < 8; ++nf) {
            const int n = nf * 16 + col, h = n >> 5, d = n & 31;
            const size_t base = ((size_t)(b * NH + h) * T_SEQ + t0 + mrow) * HD + d;
#pragma unroll
            for (int r = 0; r < 4; ++r)
                outp[base + (size_t)r * HD] = f2bf(acc[nf][r] * sc);
        }
    } else {
#pragma unroll
        for (int nf = 0; nf < 8; ++nf) {
            const int n = nf * 16 + col;
            *(ull*)(&vt[n * VR + mrow]) = pk4(acc[nf][0], acc[nf][1], acc[nf][2], acc[nf][3]);
        }
        __syncthreads();
        for (int i = 0; i < 16; ++i) {
            const int idx = tid + i * 256;
            const int c = idx >> 5, dw = idx & 31;
            const int h2 = c >> 5, d2 = c & 31;
            const unsigned v0 = *(const unsigned*)(&vt[c * VR + dw * 2]);
            *(unsigned*)(vtb + ((size_t)(b * NH + h2) * HD + d2) * T_SEQ + t0 + dw * 2) = v0;
        }
    }
}

// ---------------------------------------------------------------------------
// Kernel 2: barrier-free split-K attention, 64 queries/wave. Grid 512 x 256.
// Block blk: hs = blk>>3 (0..63): qt = 31-(hs>>1) [heavy first], s = hs&1;
// wave w owns bh = (blk&7)*4+w, queries qt*64..qt*64+63 (4 x 16-frags),
// K-tile range [kt0,kt1) of the qtile's ntk=qt+1 tiles. Writes UNNORMALIZED
// fp32 y-partial + l-partial for its half.
// ---------------------------------------------------------------------------
__global__ __launch_bounds__(256) void attn(const unsigned short* __restrict__ qb,
                                            const unsigned short* __restrict__ kb,
                                            const unsigned short* __restrict__ vtb,
                                            float* __restrict__ yp0,
                                            float* __restrict__ yp1,
                                            float* __restrict__ l0,
                                            float* __restrict__ l1) {
    const int tid = threadIdx.x;
    const int wave = tid >> 6;
    const int lane = tid & 63;
    const int col = lane & 15;
    const int quad = lane >> 4;
    const int blk = blockIdx.x;
    const int hs = blk >> 3;                  // 0..63
    const int qt = 31 - (hs >> 1);            // q-tile of 64, heavy first
    const int s = hs & 1;                     // K-half
    const int bh = ((blk & 7) << 2) + wave;
    const int q0 = qt * 64;
    const int ntk = qt + 1;                   // 64-key tiles covering [0, q0+63]
    const int n0 = (ntk + 1) >> 1;
    const int kt0 = s ? n0 : 0;
    const int kt1 = s ? ntk : n0;
    const int nloc = kt1 - kt0;

    const unsigned short* kbase = kb + (size_t)bh * T_SEQ * HD;
    const unsigned short* vbase = vtb + (size_t)bh * HD * T_SEQ;

    bh8 qfrag[4];
#pragma unroll
    for (int mi = 0; mi < 4; ++mi)
        qfrag[mi] = *(const bh8*)(qb + ((size_t)bh * T_SEQ + q0 + mi * 16 + col) * HD + quad * 8);

    f4 yacc[4][2];
#pragma unroll
    for (int mi = 0; mi < 4; ++mi)
#pragma unroll
        for (int dh = 0; dh < 2; ++dh) yacc[mi][dh] = (f4){0.f, 0.f, 0.f, 0.f};
    float lsum[4] = {0.f, 0.f, 0.f, 0.f};

    // two NAMED buffer sets -> compile-time indices only (R9 lesson: runtime
    // indexing demotes to scratch)
    bh8 kfA[4], kfB[4];
    bh4 vfA[4][2], vfB[4][2];

    auto prefetch = [&](bh8 (&KF)[4], bh4 (&VF)[4][2], int kt) {
        const int kn = kt * 64;
#pragma unroll
        for (int f = 0; f < 4; ++f) {
            KF[f] = *(const bh8*)(kbase + (size_t)(kn + f * 16 + col) * HD + quad * 8);
            VF[f][0] = *(const bh4*)(vbase + (size_t)col * T_SEQ + kn + f * 16 + quad * 4);
            VF[f][1] = *(const bh4*)(vbase + (size_t)(16 + col) * T_SEQ + kn + f * 16 + quad * 4);
        }
    };
    auto compute = [&](const bh8 (&KF)[4], const bh4 (&VF)[4][2]) {
#pragma unroll
        for (int mi = 0; mi < 4; ++mi)
#pragma unroll
            for (int f = 0; f < 4; ++f) {
                f4 z = {0.f, 0.f, 0.f, 0.f};
                z = __builtin_amdgcn_mfma_f32_16x16x32_bf16(KF[f], qfrag[mi], z, 0, 0, 0);
                float p[4];
#pragma unroll
                for (int r = 0; r < 4; ++r) p[r] = __builtin_amdgcn_exp2f(z[r]);
                lsum[mi] += p[0] + p[1] + p[2] + p[3];
                union { unsigned u[2]; bh4 v; } pf;
                pf.u[0] = pk2(p[0], p[1]);
                pf.u[1] = pk2(p[2], p[3]);
                yacc[mi][0] = __builtin_amdgcn_mfma_f32_16x16x16bf16_1k(VF[f][0], pf.v, yacc[mi][0], 0, 0, 0);
                yacc[mi][1] = __builtin_amdgcn_mfma_f32_16x16x16bf16_1k(VF[f][1], pf.v, yacc[mi][1], 0, 0, 0);
            }
    };
    auto compute_masked = [&](const bh8 (&KF)[4], const bh4 (&VF)[4][2], int kb0) {
#pragma unroll
        for (int mi = 0; mi < 4; ++mi)
#pragma unroll
            for (int f = 0; f < 4; ++f) {
                const int dlt = kb0 + f * 16 - q0 - mi * 16;  // wave-uniform
                if (dlt > 0) continue;                        // fully masked chunk
                const bool edge = (dlt == 0);
                f4 z = {0.f, 0.f, 0.f, 0.f};
                z = __builtin_amdgcn_mfma_f32_16x16x32_bf16(KF[f], qfrag[mi], z, 0, 0, 0);
                float p[4];
#pragma unroll
                for (int r = 0; r < 4; ++r) {
                    const float e = __builtin_amdgcn_exp2f(z[r]);
                    p[r] = (edge && (quad * 4 + r > col)) ? 0.f : e;
                }
                lsum[mi] += p[0] + p[1] + p[2] + p[3];
                union { unsigned u[2]; bh4 v; } pf;
                pf.u[0] = pk2(p[0], p[1]);
                pf.u[1] = pk2(p[2], p[3]);
                yacc[mi][0] = __builtin_amdgcn_mfma_f32_16x16x16bf16_1k(VF[f][0], pf.v, yacc[mi][0], 0, 0, 0);
                yacc[mi][1] = __builtin_amdgcn_mfma_f32_16x16x16bf16_1k(VF[f][1], pf.v, yacc[mi][1], 0, 0, 0);
            }
    };

    if (nloc > 0) {
        prefetch(kfA, vfA, kt0);
        for (int i = 0; i < nloc; i += 2) {
            const bool hasB = (i + 1 < nloc);
            if (hasB) prefetch(kfB, vfB, kt0 + i + 1);
            if (kt0 + i == ntk - 1) compute_masked(kfA, vfA, (kt0 + i) * 64);
            else                    compute(kfA, vfA);
            if (hasB) {
                if (i + 2 < nloc) prefetch(kfA, vfA, kt0 + i + 2);
                if (kt0 + i + 1 == ntk - 1) compute_masked(kfB, vfB, (kt0 + i + 1) * 64);
                else                        compute(kfB, vfB);
            }
        }
    }

    // epilogue: partial l (quad-reduced) + unnormalized fp32 y-partial
    const int bb = bh >> 2, hh = bh & 3;
    float* ypw = s ? yp1 : yp0;
    float* lw  = s ? l1  : l0;
#pragma unroll
    for (int mi = 0; mi < 4; ++mi) {
        float t = lsum[mi];
        t += __shfl_xor(t, 16);
        t += __shfl_xor(t, 32);
        if (quad == 0) lw[(size_t)bh * T_SEQ + q0 + mi * 16 + col] = t;
        const size_t row = (size_t)bb * T_SEQ + q0 + mi * 16 + col;
#pragma unroll
        for (int dh = 0; dh < 2; ++dh)
            *(f4*)(ypw + row * C_EMBD + hh * HD + dh * 16 + quad * 4) = yacc[mi][dh];
    }
}

// ---------------------------------------------------------------------------
// Kernel 3: out = ((yp0+yp1)/l) @ w_proj + b_proj via MFMA. Grid 256.
// Normalization folded into LDS staging (l is per-(row,head) scalar).
// ---------------------------------------------------------------------------
__global__ __launch_bounds__(256) void out_mfma(const float* __restrict__ yp0,
                                                const float* __restrict__ yp1,
                                                const float* __restrict__ l0,
                                                const float* __restrict__ l1,
                                                const float* __restrict__ w,
                                                const float* __restrict__ bias,
                                                float* __restrict__ out) {
    constexpr int YR = 136;
    constexpr int WR = 136;
    __shared__ __align__(16) unsigned short ys[64 * YR];
    __shared__ __align__(16) unsigned short wt[128 * WR];
    __shared__ float linv[64][4];

    const int mt = blockIdx.x;
    const int row0 = mt * 64;
    const int tid = threadIdx.x;
    const int wave = tid >> 6;
    const int lane = tid & 63;
    const int col = lane & 15;
    const int quad = lane >> 4;

    {   // per-(row, head) 1/l
        const int row = tid >> 2, h = tid & 3;
        const int gt = row0 + row, b = gt >> 11, t = gt & 2047;
        const size_t idx = ((size_t)(b * NH + h)) * T_SEQ + t;
        linv[row][h] = 1.0f / (l0[idx] + l1[idx]);
    }
    __syncthreads();

    // stage y = (yp0+yp1)*linv -> bf16 LDS
    for (int i = 0; i < 8; ++i) {
        const int idx = tid + i * 256;           // over 64 rows x 32 float4
        const int row = idx >> 5, c4 = idx & 31;
        const size_t base = (size_t)(row0 + row) * C_EMBD + c4 * 4;
        const float4 a = *(const float4*)(yp0 + base);
        const float4 b = *(const float4*)(yp1 + base);
        const float inv = linv[row][c4 >> 3];
        *(ull*)(&ys[row * YR + c4 * 4]) = pk4((a.x + b.x) * inv, (a.y + b.y) * inv,
                                              (a.z + b.z) * inv, (a.w + b.w) * inv);
    }
    for (int i = 0; i < 16; ++i) {
        const int idx = tid + i * 256;
        const int n = idx & 127, k4 = idx >> 7;
        const float w0 = w[(k4 * 4 + 0) * C_EMBD + n];
        const float w1 = w[(k4 * 4 + 1) * C_EMBD + n];
        const float w2 = w[(k4 * 4 + 2) * C_EMBD + n];
        const float w3 = w[(k4 * 4 + 3) * C_EMBD + n];
        *(ull*)(&wt[n * WR + k4 * 4]) = pk4(w0, w1, w2, w3);
    }
    __syncthreads();

    f4 acc[8];
#pragma unroll
    for (int nf = 0; nf < 8; ++nf) {
        const float bv = bias[nf * 16 + col];
        acc[nf] = (f4){bv, bv, bv, bv};
    }
#pragma unroll
    for (int ch = 0; ch < 4; ++ch) {
        const bh8 af = *(const bh8*)(&ys[(wave * 16 + col) * YR + ch * 32 + quad * 8]);
#pragma unroll
        for (int nf = 0; nf < 8; ++nf) {
            const bh8 bf = *(const bh8*)(&wt[(nf * 16 + col) * WR + ch * 32 + quad * 8]);
            acc[nf] = __builtin_amdgcn_mfma_f32_16x16x32_bf16(af, bf, acc[nf], 0, 0, 0);
        }
    }

    const int mrow = wave * 16 + quad * 4;
#pragma unroll
    for (int nf = 0; nf < 8; ++nf)
#pragma unroll
        for (int r = 0; r < 4; ++r)
            out[(size_t)(row0 + mrow + r) * C_EMBD + nf * 16 + col] = acc[nf][r];
}

extern "C" void kernel_launch(void* const* d_in, const int* in_sizes, int n_in,
                              void* d_out, int out_size, void* d_ws, size_t ws_size,
                              hipStream_t stream) {
    const float* x      = (const float*)d_in[0];
    const float* w_qkv  = (const float*)d_in[1];
    const float* b_qkv  = (const float*)d_in[2];
    const float* w_proj = (const float*)d_in[3];
    const float* b_proj = (const float*)d_in[4];
    float* out = (float*)d_out;

    unsigned short* qb  = (unsigned short*)d_ws;                   // 4 MB
    unsigned short* kb  = qb + (size_t)BHT * T_SEQ * HD;           // 4 MB
    unsigned short* vtb = kb + (size_t)BHT * T_SEQ * HD;           // 4 MB
    char* p = (char*)d_ws + (size_t)3 * BHT * T_SEQ * HD * 2;      // 12 MB
    float* yp0 = (float*)p;                                        // 8 MB
    float* yp1 = (float*)(p + (size_t)8 * 1024 * 1024);            // 8 MB
    float* l0  = (float*)(p + (size_t)16 * 1024 * 1024);           // 256 KB
    float* l1  = (float*)(p + (size_t)16 * 1024 * 1024 + 256 * 1024);

    qkv_mfma<<<dim3(3, 256), 256, 0, stream>>>(x, w_qkv, b_qkv, qb, kb, vtb);
    attn<<<512, 256, 0, stream>>>(qb, kb, vtb, yp0, yp1, l0, l1);
    out_mfma<<<256, 256, 0, stream>>>(yp0, yp1, l0, l1, w_proj, b_proj, out);
}